// Round 7
// baseline (310.093 us; speedup 1.0000x reference)
//
#include <hip/hip_runtime.h>
#include <hip/hip_cooperative_groups.h>
#include <math.h>

namespace cg = cooperative_groups;

#ifndef M_PI
#define M_PI 3.14159265358979323846
#endif

namespace {
constexpr int kNSamples = 524288;
constexpr int kNGrains  = 4096;
constexpr int kGrainN   = 16384;
constexpr int kTile     = 512;                  // 2 samples/thread * 256 threads
constexpr int kNTiles   = kNSamples / kTile;    // 1024 blocks = 4/CU (exact fit)
constexpr int kGuard    = 1024;                 // guard entries each side (phase=0)
constexpr int kTabN     = kGrainN + 2 * kGuard; // 18432
constexpr int kSortBlocks = 128;                // 32 grains per block, 8-way chunks
constexpr int kTabBlocks  = kTabN / 256;        // 72

// ws layout (bytes)
constexpr size_t PART_OFF = 0;                        // double[kNTiles]   8 KB
constexpr size_t ONS_OFF  = PART_OFF + 8 * kNTiles;   // int[kNGrains]    16 KB
constexpr size_t GR_OFF   = ONS_OFF + 4 * kNGrains;   // float4[kNGrains] 64 KB
constexpr size_t TAB_OFF  = GR_OFF + 16 * kNGrains;   // float[kTabN]     72 KB
}  // namespace

// Force a (uniform) index into a VGPR so the compiler emits a vector
// global_load (vmcnt, in-order, precise waits) instead of s_load (lgkmcnt,
// out-of-order -> conservative full drains that serialize the pipeline).
__device__ __forceinline__ float4 vload4(const float4* p, int idx) {
  asm volatile("" : "+v"(idx));
  return p[idx];
}

__global__ __launch_bounds__(256, 4) void k_fused(
    const float* __restrict__ dens_p, const float* __restrict__ slope_p,
    const float* __restrict__ f0p, const int* __restrict__ onsets,
    char* __restrict__ ws, float* __restrict__ out) {
  __shared__ int    s_sons[kNGrains];   // 16 KB: phase A sort keys; phase C f64 red
  __shared__ int    s_rank[32][9];      // padded
  __shared__ double s_wpart[4];

  const int tid = threadIdx.x;
  const int bid = blockIdx.x;

  int*    ONS      = (int*)(ws + ONS_OFF);
  float4* GRm      = (float4*)(ws + GR_OFF);
  float*  TABF     = (float*)(ws + TAB_OFF);
  double* partials = (double*)(ws + PART_OFF);

  // ---------------- Phase A: setup ----------------
  if (bid < kSortBlocks) {
    // rank[g] = #{h : (onset[h],h) < (onset[g],g)} -- deterministic, no atomics
    for (int i = tid; i < kNGrains; i += 256) s_sons[i] = onsets[i];
    __syncthreads();
    const int gi = tid & 31, ck = tid >> 5;   // 32 grains x 8 key-chunks
    const int g  = bid * 32 + gi;
    const int og = s_sons[g];
    int pr = 0;
    const int h0 = ck * 512;
#pragma unroll 8
    for (int h = h0; h < h0 + 512; ++h) {
      const int oh = s_sons[h];
      pr += (int)(oh < og) | ((int)(oh == og) & (int)(h < g));
    }
    s_rank[gi][ck] = pr;
    __syncthreads();
    if (tid < 32) {
      const int gg = bid * 32 + tid;
      int rank = 0;
#pragma unroll
      for (int k2 = 0; k2 < 8; ++k2) rank += s_rank[tid][k2];
      // amps strictly decreasing => max = amps[0]
      const double d    = (double)dens_p[0];
      const double off  = 0.25 * d + 0.75 * d * d;
      const double c2   = 2.0 * (1.0 - d) * 4096.0;
      const double amp  = 1.0 / (1.0 + exp(c2 * ((double)gg / 4096.0 - off)));
      const double amp0 = 1.0 / (1.0 + exp(c2 * (0.0 - off)));
      const float f0g = f0p[gg];
      const float cg  = (float)(amp / amp0) / sqrtf(f0g);
      ONS[rank] = s_sons[gg];
      GRm[rank] = make_float4(__int_as_float(s_sons[gg]), f0g, cg, 0.0f);
    }
  } else if (bid < kSortBlocks + kTabBlocks) {
    // phase table (f64 -> f32); guards = 0 => sin(f0*0)=0 annihilates OOB
    const int e = (bid - kSortBlocks) * 256 + tid;
    const int l = e - kGuard;
    float v = 0.0f;
    if ((unsigned)l < (unsigned)kGrainN) {
      const double ts    = (double)slope_p[0];
      const double gamma = tan(ts * M_PI / 2.0) * (44100.0 / (12.0 * 256.0)) / 4.0;
      const float  tf    = (float)l / 44100.0f - 0.18575963718820862f;  // ref f32 t
      const double ph = (gamma == 0.0) ? (double)tf
                                       : expm1(gamma * (double)tf) / gamma;
      v = (float)ph;
    }
    TABF[e] = v;
  }

  cg::this_grid().sync();

  // ---------------- Phase B: main accumulation ----------------
  const int s = bid * kTile;
  int lo, hi;
  {
    int a = 0, b = kNGrains;
    const int t1 = s - kGrainN;
    while (a < b) { int m = (a + b) >> 1; if (ONS[m] > t1) b = m; else a = m + 1; }
    lo = a;
    a = lo; b = kNGrains;
    const int t2 = s + kTile - 1;
    while (a < b) { int m = (a + b) >> 1; if (ONS[m] > t2) b = m; else a = m + 1; }
    hi = a;
  }
  lo = __builtin_amdgcn_readfirstlane(lo);
  hi = __builtin_amdgcn_readfirstlane(hi);

  const int p0 = s + tid;               // this thread's sample 0 (sample 1 = +256)
  const float* TABG = TABF + kGuard;
  float a0 = 0.0f, a1 = 0.0f;

  if (lo < hi) {
    const int last = hi - 1;
    // pipeline: GR queue depth 4 (vector loads), table depth 2
    float4 prA = vload4(GRm, lo);
    float4 prB = vload4(GRm, min(lo + 1, last));
    float4 prC = vload4(GRm, min(lo + 2, last));
    float4 prD = vload4(GRm, min(lo + 3, last));
    int onA = __builtin_amdgcn_readfirstlane(__float_as_int(prA.x));
    int onB = __builtin_amdgcn_readfirstlane(__float_as_int(prB.x));
    const float* pA = TABG - onA;
    const float* pB = TABG - onB;
    float tA0 = pA[p0], tA1 = pA[p0 + 256];
    float tB0 = pB[p0], tB1 = pB[p0 + 256];

    for (int j = lo; j < hi; ++j) {
      // issue GR[j+4]; issue table loads for grain j+2 (params arrived 2 iters ago)
      float4 prE = vload4(GRm, min(j + 4, last));
      const int onC = __builtin_amdgcn_readfirstlane(__float_as_int(prC.x));
      const float* pC = TABG - onC;
      const float tC0 = pC[p0], tC1 = pC[p0 + 256];

      // compute grain j (table values issued 2 iterations ago)
      const float f0 = prA.y, c = prA.z;
      const float lf   = (float)(p0 - onA);
      const float arg0 = lf * (1.0f / 16384.0f);
      const float arg1 = arg0 + (256.0f / 16384.0f);
      const float sv0 = __builtin_amdgcn_sinf(__builtin_amdgcn_fractf(f0 * tA0));
      const float sv1 = __builtin_amdgcn_sinf(__builtin_amdgcn_fractf(f0 * tA1));
      const float w20 = fmaf(-0.5f, __builtin_amdgcn_cosf(arg0), 0.5f);
      const float w21 = fmaf(-0.5f, __builtin_amdgcn_cosf(arg1), 0.5f);
      a0 = fmaf(c * w20, sv0, a0);
      a1 = fmaf(c * w21, sv1, a1);

      // rotate pipeline
      prA = prB; prB = prC; prC = prD; prD = prE;
      onA = onB; onB = onC;
      tA0 = tB0; tA1 = tB1; tB0 = tC0; tB1 = tC1;
    }
  }

  // per-tile sum of squares (f64) -> partials[bid]
  double p2 = (double)a0 * a0 + (double)a1 * a1;
  for (int off2 = 32; off2 > 0; off2 >>= 1) p2 += __shfl_down(p2, off2);
  if ((tid & 63) == 0) s_wpart[tid >> 6] = p2;
  __syncthreads();
  if (tid == 0) partials[bid] = s_wpart[0] + s_wpart[1] + s_wpart[2] + s_wpart[3];

  cg::this_grid().sync();

  // ---------------- Phase C: norm + scale + store ----------------
  // every block reduces the same 1024 doubles in the same order -> identical scale
  double sum = 0.0;
  for (int t = tid; t < kNTiles; t += 256) sum += partials[t];
  double* red = reinterpret_cast<double*>(s_sons);  // reuse 16 KB LDS
  red[tid] = sum;
  __syncthreads();
  for (int st = 128; st > 0; st >>= 1) {
    if (tid < st) red[tid] += red[tid + st];
    __syncthreads();
  }
  const float sc = (float)(1.0 / sqrt(red[0]));
  out[p0]       = a0 * sc;
  out[p0 + 256] = a1 * sc;
}

extern "C" void kernel_launch(void* const* d_in, const int* in_sizes, int n_in,
                              void* d_out, int out_size, void* d_ws, size_t ws_size,
                              hipStream_t stream) {
  const float* dens   = (const float*)d_in[0];
  const float* slope  = (const float*)d_in[1];
  const float* f0     = (const float*)d_in[2];
  const int*   onsets = (const int*)d_in[3];
  float* out = (float*)d_out;
  char*  ws  = (char*)d_ws;

  void* args[] = {(void*)&dens, (void*)&slope, (void*)&f0,
                  (void*)&onsets, (void*)&ws, (void*)&out};
  hipLaunchCooperativeKernel(reinterpret_cast<const void*>(&k_fused),
                             dim3(kNTiles), dim3(256), args, 0, stream);
}

// Round 8
// 96.716 us; speedup vs baseline: 3.2062x; 3.2062x over previous
//
#include <hip/hip_runtime.h>
#include <math.h>

#ifndef M_PI
#define M_PI 3.14159265358979323846
#endif

namespace {
constexpr int kNSamples = 524288;
constexpr int kNGrains  = 4096;
constexpr int kGrainN   = 16384;
constexpr int kTile     = 256;                  // 1 sample/thread
constexpr int kNTiles   = kNSamples / kTile;    // 2048 blocks -> 8/CU
constexpr int kGuard    = 1024;                 // guard entries each side (phase=0)
constexpr int kTabN     = kGrainN + 2 * kGuard; // 18432

// ws layout (bytes), 16-aligned
constexpr size_t PART_OFF = 0;                        // double[kNTiles]  16 KB
constexpr size_t ONS_OFF  = PART_OFF + 8 * kNTiles;   // int[kNGrains]    16 KB
constexpr size_t F0C_OFF  = ONS_OFF + 4 * kNGrains;   // float2[kNGrains] 32 KB
constexpr size_t TAB_OFF  = F0C_OFF + 8 * kNGrains;   // float[kTabN]     72 KB
// end = TAB_OFF + 4*kTabN = 139,264 bytes
}  // namespace

// Fused setup kernel (round-6 proven structure). Blocks [0,64): rank-sort +
// per-grain coefs. Blocks [64,64+72): phase table (f64 -> f32), guards = 0.
// rank[g] = #{h : (onset[h],h) < (onset[g],g)} -- deterministic, no atomics.
// max(amps) == amps[0] (amps strictly decreasing in g).
// Guard phase 0 => sin(2*pi*f0*0) = 0 => OOB contributions vanish w/o a mask.
__global__ __launch_bounds__(256) void k_setup(const float* __restrict__ dens_p,
                                               const float* __restrict__ slope_p,
                                               const float* __restrict__ f0,
                                               const int* __restrict__ onsets,
                                               void* wsv) {
  char* ws = (char*)wsv;
  const int tid = threadIdx.x;

  if (blockIdx.x >= 64) {
    // ---- phase table ----
    const int e = (blockIdx.x - 64) * 256 + tid;
    const int l = e - kGuard;
    float v = 0.0f;
    if ((unsigned)l < (unsigned)kGrainN) {
      const double ts    = (double)slope_p[0];
      const double gamma = tan(ts * M_PI / 2.0) * (44100.0 / (12.0 * 256.0)) / 4.0;
      const float  tf    = (float)l / 44100.0f - 0.18575963718820862f;  // ref f32 t
      const double ph = (gamma == 0.0) ? (double)tf
                                       : expm1(gamma * (double)tf) / gamma;
      v = (float)ph;
    }
    ((float*)(ws + TAB_OFF))[e] = v;
    return;
  }

  // ---- rank sort + coefs ----
  __shared__ int sons[kNGrains];        // 16 KB
  __shared__ int srank[64][5];          // padded

  for (int i = tid; i < kNGrains; i += 256) sons[i] = onsets[i];
  __syncthreads();

  const int gi = tid & 63;
  const int g  = blockIdx.x * 64 + gi;
  const int ck = tid >> 6;              // 0..3
  const int og = sons[g];

  int pr = 0;
  const int h0 = ck * 1024;
#pragma unroll 8
  for (int h = h0; h < h0 + 1024; ++h) {
    const int oh = sons[h];
    pr += (int)(oh < og) | ((int)(oh == og) & (int)(h < g));
  }
  srank[gi][ck] = pr;
  __syncthreads();

  if (tid < 64) {
    const int gg   = blockIdx.x * 64 + tid;
    const int rank = srank[tid][0] + srank[tid][1] + srank[tid][2] + srank[tid][3];

    const double d    = (double)dens_p[0];
    const double off  = 0.25 * d + 0.75 * d * d;
    const double c2   = 2.0 * (1.0 - d) * 4096.0;
    const double amp  = 1.0 / (1.0 + exp(c2 * ((double)gg / 4096.0 - off)));
    const double amp0 = 1.0 / (1.0 + exp(c2 * (0.0 - off)));  // max amp

    const float f0g = f0[gg];
    const float cg  = (float)(amp / amp0) / sqrtf(f0g);
    ((int*)(ws + ONS_OFF))[rank]    = sons[gg];
    ((float2*)(ws + F0C_OFF))[rank] = make_float2(f0g, cg);
  }
}

// Main kernel: 1 sample/thread, 8 blocks/CU, explicit load queues.
// Queue invariants at top of iter j:
//   on_k = onset(j+k), k=0..4   (SGPR, s_load)
//   fc_k = {f0,c}(j+k), k=0..1  (SGPR pair)
//   t_k  = phase table value for grain j+k at this sample, k=0..2 (VGPR)
// Loads issued per iter: ONS[j+5], F0C[j+2], TAB for grain j+3 (base from on3,
// loaded 2 iters earlier). Load->use distances: table 3 iters, s_loads 2 iters.
__global__ __launch_bounds__(256, 8) void k_main(const int* __restrict__ ONS,
                                                 const float2* __restrict__ F0C,
                                                 const float* __restrict__ TABF,
                                                 double* __restrict__ partials,
                                                 float* __restrict__ out) {
  const int bid = blockIdx.x;
  const int tid = threadIdx.x;
  const int s   = bid * kTile;

  // grains overlapping [s, s+kTile): onset in (s - kGrainN, s + kTile - 1]
  int lo, hi;
  {
    int a = 0, b = kNGrains;
    const int t1 = s - kGrainN;
    while (a < b) { int m = (a + b) >> 1; if (ONS[m] > t1) b = m; else a = m + 1; }
    lo = a;
    a = lo; b = kNGrains;
    const int t2 = s + kTile - 1;
    while (a < b) { int m = (a + b) >> 1; if (ONS[m] > t2) b = m; else a = m + 1; }
    hi = a;
  }
  lo = __builtin_amdgcn_readfirstlane(lo);
  hi = __builtin_amdgcn_readfirstlane(hi);

  const int p0 = s + tid;
  const float* TABG = TABF + kGuard;
  float acc = 0.0f;

  if (lo < hi) {
    const int last = hi - 1;

    int on0 = ONS[lo];
    int on1 = ONS[min(lo + 1, last)];
    int on2 = ONS[min(lo + 2, last)];
    int on3 = ONS[min(lo + 3, last)];
    int on4 = ONS[min(lo + 4, last)];
    float2 fc0 = F0C[lo];
    float2 fc1 = F0C[min(lo + 1, last)];
    float t0 = (TABG - on0)[p0];
    float t1 = (TABG - on1)[p0];
    float t2 = (TABG - on2)[p0];

#pragma unroll 4
    for (int j = lo; j < hi; ++j) {
      // issue loads first (distances: table 3 iters, scalar 2 iters)
      const float tn  = (TABG - on3)[p0];
      const int   onn = ONS[__builtin_amdgcn_readfirstlane(min(j + 5, last))];
      const float2 fcn = F0C[__builtin_amdgcn_readfirstlane(min(j + 2, last))];

      // compute grain j
      const float lf = (float)(p0 - on0);
      const float w2 = fmaf(-0.5f, __builtin_amdgcn_cosf(lf * (1.0f / 16384.0f)), 0.5f);
      const float sv = __builtin_amdgcn_sinf(__builtin_amdgcn_fractf(fc0.x * t0));
      acc = fmaf(fc0.y * w2, sv, acc);

      // rotate queues (renamed by unroll)
      on0 = on1; on1 = on2; on2 = on3; on3 = on4; on4 = onn;
      fc0 = fc1; fc1 = fcn;
      t0 = t1; t1 = t2; t2 = tn;
    }
  }

  out[p0] = acc;

  // per-tile sum of squares (f64) -> partials[bid]
  double p2 = (double)acc * acc;
  for (int off2 = 32; off2 > 0; off2 >>= 1) p2 += __shfl_down(p2, off2);
  __shared__ double wpart[4];
  if ((tid & 63) == 0) wpart[tid >> 6] = p2;
  __syncthreads();
  if (tid == 0) partials[bid] = wpart[0] + wpart[1] + wpart[2] + wpart[3];
}

// Fused norm + scale: every block reduces the same 2048 partials in the same
// order (deterministic, identical result), then scales its 1024-sample chunk.
__global__ __launch_bounds__(256) void k_finalscale(const double* __restrict__ partials,
                                                    float4* __restrict__ out) {
  __shared__ double red[256];
  const int tid = threadIdx.x;
  double sum = 0.0;
#pragma unroll
  for (int k = 0; k < kNTiles / 256; ++k) sum += partials[tid + k * 256];
  red[tid] = sum;
  __syncthreads();
  for (int st = 128; st > 0; st >>= 1) {
    if (tid < st) red[tid] += red[tid + st];
    __syncthreads();
  }
  const float sc = (float)(1.0 / sqrt(red[0]));
  const int i = blockIdx.x * 256 + tid;
  float4 v = out[i];
  v.x *= sc; v.y *= sc; v.z *= sc; v.w *= sc;
  out[i] = v;
}

extern "C" void kernel_launch(void* const* d_in, const int* in_sizes, int n_in,
                              void* d_out, int out_size, void* d_ws, size_t ws_size,
                              hipStream_t stream) {
  const float* dens   = (const float*)d_in[0];
  const float* slope  = (const float*)d_in[1];
  const float* f0     = (const float*)d_in[2];
  const int*   onsets = (const int*)d_in[3];
  float* out = (float*)d_out;
  char*  ws  = (char*)d_ws;

  hipLaunchKernelGGL(k_setup, dim3(64 + kTabN / 256), dim3(256), 0, stream,
                     dens, slope, f0, onsets, d_ws);
  hipLaunchKernelGGL(k_main, dim3(kNTiles), dim3(256), 0, stream,
                     (const int*)(ws + ONS_OFF), (const float2*)(ws + F0C_OFF),
                     (const float*)(ws + TAB_OFF), (double*)(ws + PART_OFF), out);
  hipLaunchKernelGGL(k_finalscale, dim3(kNSamples / 1024), dim3(256), 0, stream,
                     (const double*)(ws + PART_OFF), (float4*)out);
}

// Round 9
// 74.471 us; speedup vs baseline: 4.1639x; 1.2987x over previous
//
#include <hip/hip_runtime.h>
#include <math.h>

#ifndef M_PI
#define M_PI 3.14159265358979323846
#endif

namespace {
constexpr int kNSamples = 524288;
constexpr int kNGrains  = 4096;
constexpr int kGrainN   = 16384;
constexpr int kTile     = 512;                  // 2 samples/thread
constexpr int kNTiles   = kNSamples / kTile;    // 1024 blocks -> 4/CU
constexpr int kGuard    = 1024;                 // guard entries each side (phase=0)
constexpr int kTabN     = kGrainN + 2 * kGuard; // 18432
constexpr int kChunk    = 512;                  // LDS grain-stage chunk (>= worst case)

// ws layout (bytes), 16-aligned
constexpr size_t PART_OFF = 0;                        // double[kNTiles]   8 KB
constexpr size_t ONS_OFF  = PART_OFF + 8 * kNTiles;   // int[kNGrains]    16 KB
constexpr size_t GR_OFF   = ONS_OFF + 4 * kNGrains;   // float4[kNGrains] 64 KB
constexpr size_t TAB_OFF  = GR_OFF + 16 * kNGrains;   // float[kTabN]     72 KB
// end = TAB_OFF + 4*kTabN = 163,840 bytes
}  // namespace

// Setup: blocks [0,64) rank-sort + coefs; blocks [64,136) phase table.
// rank[g] = #{h : (onset[h],h) < (onset[g],g)} -- deterministic, no atomics.
// max(amps) == amps[0] (amps strictly decreasing in g).
// Guard phase 0 => sin(2*pi*f0*0) = 0 => OOB contributions vanish w/o a mask.
__global__ __launch_bounds__(256) void k_setup(const float* __restrict__ dens_p,
                                               const float* __restrict__ slope_p,
                                               const float* __restrict__ f0,
                                               const int* __restrict__ onsets,
                                               void* wsv) {
  char* ws = (char*)wsv;
  const int tid = threadIdx.x;

  if (blockIdx.x >= 64) {
    const int e = (blockIdx.x - 64) * 256 + tid;
    const int l = e - kGuard;
    float v = 0.0f;
    if ((unsigned)l < (unsigned)kGrainN) {
      const double ts    = (double)slope_p[0];
      const double gamma = tan(ts * M_PI / 2.0) * (44100.0 / (12.0 * 256.0)) / 4.0;
      const float  tf    = (float)l / 44100.0f - 0.18575963718820862f;  // ref f32 t
      const double ph = (gamma == 0.0) ? (double)tf
                                       : expm1(gamma * (double)tf) / gamma;
      v = (float)ph;
    }
    ((float*)(ws + TAB_OFF))[e] = v;
    return;
  }

  __shared__ int sons[kNGrains];        // 16 KB
  __shared__ int srank[64][5];          // padded

  for (int i = tid; i < kNGrains; i += 256) sons[i] = onsets[i];
  __syncthreads();

  const int gi = tid & 63;
  const int g  = blockIdx.x * 64 + gi;
  const int ck = tid >> 6;              // 0..3
  const int og = sons[g];

  int pr = 0;
  const int h0 = ck * 1024;
#pragma unroll 8
  for (int h = h0; h < h0 + 1024; ++h) {
    const int oh = sons[h];
    pr += (int)(oh < og) | ((int)(oh == og) & (int)(h < g));
  }
  srank[gi][ck] = pr;
  __syncthreads();

  if (tid < 64) {
    const int gg   = blockIdx.x * 64 + tid;
    const int rank = srank[tid][0] + srank[tid][1] + srank[tid][2] + srank[tid][3];

    const double d    = (double)dens_p[0];
    const double off  = 0.25 * d + 0.75 * d * d;
    const double c2   = 2.0 * (1.0 - d) * 4096.0;
    const double amp  = 1.0 / (1.0 + exp(c2 * ((double)gg / 4096.0 - off)));
    const double amp0 = 1.0 / (1.0 + exp(c2 * (0.0 - off)));  // max amp

    const float f0g = f0[gg];
    const float cg  = (float)(amp / amp0) / sqrtf(f0g);
    ((int*)(ws + ONS_OFF))[rank]    = sons[gg];
    ((float4*)(ws + GR_OFF))[rank]  = make_float4(__int_as_float(sons[gg]), f0g, cg, 0.0f);
  }
}

// Main: 2 samples/thread. Grain records staged in LDS (ds_read = in-order ->
// counted lgkmcnt waits, no drains). Table loads: depth-3 queue, SGPR base via
// readfirstlane (distance 3 -> counted vmcnt). Unroll renames queue rotations.
__global__ __launch_bounds__(256, 4) void k_main(const int* __restrict__ ONS,
                                                 const float4* __restrict__ GR,
                                                 const float* __restrict__ TABF,
                                                 double* __restrict__ partials,
                                                 float* __restrict__ out) {
  __shared__ float4 sg[kChunk];   // 8 KB: staged grain records {onset,f0,c,_}
  __shared__ double wpart[4];

  const int bid = blockIdx.x;
  const int tid = threadIdx.x;
  const int s   = bid * kTile;

  // grains overlapping [s, s+kTile): onset in (s - kGrainN, s + kTile - 1]
  int lo, hi;
  {
    int a = 0, b = kNGrains;
    const int t1 = s - kGrainN;
    while (a < b) { int m = (a + b) >> 1; if (ONS[m] > t1) b = m; else a = m + 1; }
    lo = a;
    a = lo; b = kNGrains;
    const int t2 = s + kTile - 1;
    while (a < b) { int m = (a + b) >> 1; if (ONS[m] > t2) b = m; else a = m + 1; }
    hi = a;
  }
  lo = __builtin_amdgcn_readfirstlane(lo);
  hi = __builtin_amdgcn_readfirstlane(hi);

  const int p0 = s + tid;
  const float* TABG = TABF + kGuard;
  float acc0 = 0.0f, acc1 = 0.0f;

  for (int base = lo; base < hi; base += kChunk) {
    const int n = min(kChunk, hi - base);   // uniform
    __syncthreads();
    for (int i = tid; i < n; i += 256) sg[i] = GR[base + i];
    __syncthreads();

    // prologue: param queue depth 4, table-value queue depth 3
    float4 q0 = sg[0];
    float4 q1 = sg[min(1, n - 1)];
    float4 q2 = sg[min(2, n - 1)];
    float4 q3 = sg[min(3, n - 1)];
    const int s0 = __builtin_amdgcn_readfirstlane(__float_as_int(q0.x));
    const int s1 = __builtin_amdgcn_readfirstlane(__float_as_int(q1.x));
    const int s2 = __builtin_amdgcn_readfirstlane(__float_as_int(q2.x));
    const float* pT0 = TABG - s0;
    const float* pT1 = TABG - s1;
    const float* pT2 = TABG - s2;
    float t00 = pT0[p0], t01 = pT0[p0 + 256];
    float t10 = pT1[p0], t11 = pT1[p0 + 256];
    float t20 = pT2[p0], t21 = pT2[p0 + 256];

#pragma unroll 4
    for (int j = 0; j < n; ++j) {
      // issue: params j+4 (LDS), table values for grain j+3 (global)
      const float4 qn = sg[min(j + 4, n - 1)];
      const int s3 = __builtin_amdgcn_readfirstlane(__float_as_int(q3.x));
      const float* pT = TABG - s3;
      const float tn0 = pT[p0], tn1 = pT[p0 + 256];

      // compute grain j (params from 4 iters ago, table values from 3)
      const int   on0  = __float_as_int(q0.x);
      const float lf   = (float)(p0 - on0);
      const float arg0 = lf * (1.0f / 16384.0f);
      const float arg1 = arg0 + (256.0f / 16384.0f);
      const float w20  = fmaf(-0.5f, __builtin_amdgcn_cosf(arg0), 0.5f);
      const float w21  = fmaf(-0.5f, __builtin_amdgcn_cosf(arg1), 0.5f);
      const float sv0  = __builtin_amdgcn_sinf(__builtin_amdgcn_fractf(q0.y * t00));
      const float sv1  = __builtin_amdgcn_sinf(__builtin_amdgcn_fractf(q0.y * t01));
      acc0 = fmaf(q0.z * w20, sv0, acc0);
      acc1 = fmaf(q0.z * w21, sv1, acc1);

      // rotate queues (renamed by unroll)
      q0 = q1; q1 = q2; q2 = q3; q3 = qn;
      t00 = t10; t01 = t11; t10 = t20; t11 = t21; t20 = tn0; t21 = tn1;
    }
  }

  out[p0]       = acc0;
  out[p0 + 256] = acc1;

  // per-tile sum of squares (f64) -> partials[bid]
  double p2 = (double)acc0 * acc0 + (double)acc1 * acc1;
  for (int off2 = 32; off2 > 0; off2 >>= 1) p2 += __shfl_down(p2, off2);
  if ((tid & 63) == 0) wpart[tid >> 6] = p2;
  __syncthreads();
  if (tid == 0) partials[bid] = wpart[0] + wpart[1] + wpart[2] + wpart[3];
}

// Fused norm + scale: every block reduces the same partials in the same order
// (deterministic, identical result), then scales its 1024-sample chunk.
__global__ __launch_bounds__(256) void k_finalscale(const double* __restrict__ partials,
                                                    float4* __restrict__ out) {
  __shared__ double red[256];
  const int tid = threadIdx.x;
  double sum = 0.0;
#pragma unroll
  for (int k = 0; k < kNTiles / 256; ++k) sum += partials[tid + k * 256];
  red[tid] = sum;
  __syncthreads();
  for (int st = 128; st > 0; st >>= 1) {
    if (tid < st) red[tid] += red[tid + st];
    __syncthreads();
  }
  const float sc = (float)(1.0 / sqrt(red[0]));
  const int i = blockIdx.x * 256 + tid;
  float4 v = out[i];
  v.x *= sc; v.y *= sc; v.z *= sc; v.w *= sc;
  out[i] = v;
}

extern "C" void kernel_launch(void* const* d_in, const int* in_sizes, int n_in,
                              void* d_out, int out_size, void* d_ws, size_t ws_size,
                              hipStream_t stream) {
  const float* dens   = (const float*)d_in[0];
  const float* slope  = (const float*)d_in[1];
  const float* f0     = (const float*)d_in[2];
  const int*   onsets = (const int*)d_in[3];
  float* out = (float*)d_out;
  char*  ws  = (char*)d_ws;

  hipLaunchKernelGGL(k_setup, dim3(64 + kTabN / 256), dim3(256), 0, stream,
                     dens, slope, f0, onsets, d_ws);
  hipLaunchKernelGGL(k_main, dim3(kNTiles), dim3(256), 0, stream,
                     (const int*)(ws + ONS_OFF), (const float4*)(ws + GR_OFF),
                     (const float*)(ws + TAB_OFF), (double*)(ws + PART_OFF), out);
  hipLaunchKernelGGL(k_finalscale, dim3(kNSamples / 1024), dim3(256), 0, stream,
                     (const double*)(ws + PART_OFF), (float4*)out);
}

// Round 10
// 70.246 us; speedup vs baseline: 4.4144x; 1.0601x over previous
//
#include <hip/hip_runtime.h>
#include <math.h>

#ifndef M_PI
#define M_PI 3.14159265358979323846
#endif

namespace {
constexpr int kNSamples = 524288;
constexpr int kNGrains  = 4096;
constexpr int kGrainN   = 16384;
constexpr int kTile     = 512;                  // 2 adjacent samples/thread
constexpr int kNTiles   = kNSamples / kTile;    // 1024 blocks -> 4/CU
constexpr int kGuard    = 1024;                 // guard entries each side ({0,0})
constexpr int kTabN     = kGrainN + 2 * kGuard; // 18432
constexpr int kChunk    = 512;                  // LDS grain-stage chunk

// ws layout (bytes), 16-aligned
constexpr size_t PART_OFF = 0;                        // double[kNTiles]    8 KB
constexpr size_t ONS_OFF  = PART_OFF + 8 * kNTiles;   // int[kNGrains]     16 KB
constexpr size_t GR_OFF   = ONS_OFF + 4 * kNGrains;   // float4[kNGrains]  64 KB
constexpr size_t TAB_OFF  = GR_OFF + 16 * kNGrains;   // float2[kTabN]    144 KB
// end = TAB_OFF + 8*kTabN = 237,568 bytes
}  // namespace

// Setup: blocks [0,64) rank-sort + coefs; blocks [64,136) table.
// rank[g] = #{h : (onset[h],h) < (onset[g],g)} -- deterministic, no atomics.
// max(amps) == amps[0] (amps strictly decreasing in g).
// Table entry e (= l + kGuard): {phase_l, sin^2(pi*l/L)}; guards {0,0} =>
// OOB contributions vanish (w2=0) with no mask in the hot loop.
__global__ __launch_bounds__(256) void k_setup(const float* __restrict__ dens_p,
                                               const float* __restrict__ slope_p,
                                               const float* __restrict__ f0,
                                               const int* __restrict__ onsets,
                                               void* wsv) {
  char* ws = (char*)wsv;
  const int tid = threadIdx.x;

  if (blockIdx.x >= 64) {
    const int e = (blockIdx.x - 64) * 256 + tid;
    const int l = e - kGuard;
    float2 v = make_float2(0.0f, 0.0f);
    if ((unsigned)l < (unsigned)kGrainN) {
      const double ts    = (double)slope_p[0];
      const double gamma = tan(ts * M_PI / 2.0) * (44100.0 / (12.0 * 256.0)) / 4.0;
      const float  tf    = (float)l / 44100.0f - 0.18575963718820862f;  // ref f32 t
      const double ph = (gamma == 0.0) ? (double)tf
                                       : expm1(gamma * (double)tf) / gamma;
      const double wv = sin(M_PI * ((double)l / 16384.0));
      v = make_float2((float)ph, (float)(wv * wv));
    }
    ((float2*)(ws + TAB_OFF))[e] = v;
    return;
  }

  __shared__ int sons[kNGrains];        // 16 KB
  __shared__ int srank[64][5];          // padded

  for (int i = tid; i < kNGrains; i += 256) sons[i] = onsets[i];
  __syncthreads();

  const int gi = tid & 63;
  const int g  = blockIdx.x * 64 + gi;
  const int ck = tid >> 6;              // 0..3
  const int og = sons[g];

  int pr = 0;
  const int h0 = ck * 1024;
#pragma unroll 8
  for (int h = h0; h < h0 + 1024; ++h) {
    const int oh = sons[h];
    pr += (int)(oh < og) | ((int)(oh == og) & (int)(h < g));
  }
  srank[gi][ck] = pr;
  __syncthreads();

  if (tid < 64) {
    const int gg   = blockIdx.x * 64 + tid;
    const int rank = srank[tid][0] + srank[tid][1] + srank[tid][2] + srank[tid][3];

    const double d    = (double)dens_p[0];
    const double off  = 0.25 * d + 0.75 * d * d;
    const double c2   = 2.0 * (1.0 - d) * 4096.0;
    const double amp  = 1.0 / (1.0 + exp(c2 * ((double)gg / 4096.0 - off)));
    const double amp0 = 1.0 / (1.0 + exp(c2 * (0.0 - off)));  // max amp

    const float f0g = f0[gg];
    const float cg  = (float)(amp / amp0) / sqrtf(f0g);
    ((int*)(ws + ONS_OFF))[rank]   = sons[gg];
    ((float4*)(ws + GR_OFF))[rank] = make_float4(__int_as_float(sons[gg]), f0g, cg, 0.0f);
  }
}

// Main: 2 ADJACENT samples/thread (p0 = s + 2*tid). Per grain-iter: one
// ds_read_b128 (params, padded -> no min), two global_load_dwordx2 from the
// SAME SGPR base (offset 0 / +8B) hitting a 4 KB L1-resident sliding window.
// Queues: params depth 4, table values depth 3; unroll renames rotations.
__global__ __launch_bounds__(256, 4) void k_main(const int* __restrict__ ONS,
                                                 const float4* __restrict__ GR,
                                                 const float2* __restrict__ TAB2,
                                                 double* __restrict__ partials,
                                                 float* __restrict__ out) {
  __shared__ float4 sg[kChunk + 8];   // staged grain records + pad
  __shared__ double wpart[4];

  const int bid = blockIdx.x;
  const int tid = threadIdx.x;
  const int s   = bid * kTile;

  // grains overlapping [s, s+kTile): onset in (s - kGrainN, s + kTile - 1]
  int lo, hi;
  {
    int a = 0, b = kNGrains;
    const int t1 = s - kGrainN;
    while (a < b) { int m = (a + b) >> 1; if (ONS[m] > t1) b = m; else a = m + 1; }
    lo = a;
    a = lo; b = kNGrains;
    const int t2 = s + kTile - 1;
    while (a < b) { int m = (a + b) >> 1; if (ONS[m] > t2) b = m; else a = m + 1; }
    hi = a;
  }
  lo = __builtin_amdgcn_readfirstlane(lo);
  hi = __builtin_amdgcn_readfirstlane(hi);

  const int p0 = s + 2 * tid;                 // samples p0, p0+1
  const float2* TG = TAB2 + kGuard;           // entry l at TG[l]
  float acc0 = 0.0f, acc1 = 0.0f;

  for (int base = lo; base < hi; base += kChunk) {
    const int n = min(kChunk, hi - base);     // uniform
    __syncthreads();
    for (int i = tid; i < n; i += 256) sg[i] = GR[base + i];
    if (tid < 8) sg[n + tid] = GR[min(base + n + tid, hi - 1)];  // valid pad
    __syncthreads();

    // prologue: params 0..3, table values for grains 0..2
    float4 q0 = sg[0], q1 = sg[1], q2 = sg[2], q3 = sg[3];
    const float2* pT0 = TG - __builtin_amdgcn_readfirstlane(__float_as_int(q0.x));
    const float2* pT1 = TG - __builtin_amdgcn_readfirstlane(__float_as_int(q1.x));
    const float2* pT2 = TG - __builtin_amdgcn_readfirstlane(__float_as_int(q2.x));
    float2 u0a = pT0[p0], u0b = pT0[p0 + 1];
    float2 u1a = pT1[p0], u1b = pT1[p0 + 1];
    float2 u2a = pT2[p0], u2b = pT2[p0 + 1];

#pragma unroll 4
    for (int j = 0; j < n; ++j) {
      // issue: params j+4 (LDS), table pair for grain j+3 (global, L1-hot)
      const float4 qn = sg[j + 4];
      const float2* pT = TG - __builtin_amdgcn_readfirstlane(__float_as_int(q3.x));
      const float2 na = pT[p0];
      const float2 nb = pT[p0 + 1];

      // compute grain j (params 4 iters old, table values 3 iters old)
      const float f0v = q0.y, cv = q0.z;
      acc0 = fmaf(cv * u0a.y,
                  __builtin_amdgcn_sinf(__builtin_amdgcn_fractf(f0v * u0a.x)), acc0);
      acc1 = fmaf(cv * u0b.y,
                  __builtin_amdgcn_sinf(__builtin_amdgcn_fractf(f0v * u0b.x)), acc1);

      // rotate queues (renamed by unroll)
      q0 = q1; q1 = q2; q2 = q3; q3 = qn;
      u0a = u1a; u0b = u1b; u1a = u2a; u1b = u2b; u2a = na; u2b = nb;
    }
  }

  // adjacent-sample float2 store (8B aligned: p0 even)
  *reinterpret_cast<float2*>(out + p0) = make_float2(acc0, acc1);

  // per-tile sum of squares (f64) -> partials[bid]
  double p2 = (double)acc0 * acc0 + (double)acc1 * acc1;
  for (int off2 = 32; off2 > 0; off2 >>= 1) p2 += __shfl_down(p2, off2);
  if ((tid & 63) == 0) wpart[tid >> 6] = p2;
  __syncthreads();
  if (tid == 0) partials[bid] = wpart[0] + wpart[1] + wpart[2] + wpart[3];
}

// Fused norm + scale: every block reduces the same partials in the same order
// (deterministic, identical result), then scales its 1024-sample chunk.
__global__ __launch_bounds__(256) void k_finalscale(const double* __restrict__ partials,
                                                    float4* __restrict__ out) {
  __shared__ double red[256];
  const int tid = threadIdx.x;
  double sum = 0.0;
#pragma unroll
  for (int k = 0; k < kNTiles / 256; ++k) sum += partials[tid + k * 256];
  red[tid] = sum;
  __syncthreads();
  for (int st = 128; st > 0; st >>= 1) {
    if (tid < st) red[tid] += red[tid + st];
    __syncthreads();
  }
  const float sc = (float)(1.0 / sqrt(red[0]));
  const int i = blockIdx.x * 256 + tid;
  float4 v = out[i];
  v.x *= sc; v.y *= sc; v.z *= sc; v.w *= sc;
  out[i] = v;
}

extern "C" void kernel_launch(void* const* d_in, const int* in_sizes, int n_in,
                              void* d_out, int out_size, void* d_ws, size_t ws_size,
                              hipStream_t stream) {
  const float* dens   = (const float*)d_in[0];
  const float* slope  = (const float*)d_in[1];
  const float* f0     = (const float*)d_in[2];
  const int*   onsets = (const int*)d_in[3];
  float* out = (float*)d_out;
  char*  ws  = (char*)d_ws;

  hipLaunchKernelGGL(k_setup, dim3(64 + kTabN / 256), dim3(256), 0, stream,
                     dens, slope, f0, onsets, d_ws);
  hipLaunchKernelGGL(k_main, dim3(kNTiles), dim3(256), 0, stream,
                     (const int*)(ws + ONS_OFF), (const float4*)(ws + GR_OFF),
                     (const float2*)(ws + TAB_OFF), (double*)(ws + PART_OFF), out);
  hipLaunchKernelGGL(k_finalscale, dim3(kNSamples / 1024), dim3(256), 0, stream,
                     (const double*)(ws + PART_OFF), (float4*)out);
}

// Round 11
// 67.230 us; speedup vs baseline: 4.6124x; 1.0449x over previous
//
#include <hip/hip_runtime.h>
#include <math.h>

#ifndef M_PI
#define M_PI 3.14159265358979323846
#endif

namespace {
constexpr int kNSamples = 524288;
constexpr int kNGrains  = 4096;
constexpr int kGrainN   = 16384;
constexpr int kTile     = 512;                  // 2 adjacent samples/thread
constexpr int kNTiles   = kNSamples / kTile;    // 1024 tiles
constexpr int kGuard    = 1024;                 // guard entries each side ({0,0})
constexpr int kTabN     = kGrainN + 2 * kGuard; // 18432
constexpr int kChunk    = 512;                  // LDS grain-stage chunk

// ws layout (bytes), 16-aligned
constexpr size_t PART_OFF = 0;                        // double[512]        4 KB
constexpr size_t ONS_OFF  = PART_OFF + 8 * 512;       // int[kNGrains]     16 KB
constexpr size_t GR_OFF   = ONS_OFF + 4 * kNGrains;   // float4[kNGrains]  64 KB
constexpr size_t TAB_OFF  = GR_OFF + 16 * kNGrains;   // float2[kTabN]    144 KB
constexpr size_t OUT2_OFF = TAB_OFF + 8 * kTabN;      // float[kNSamples]   2 MB
constexpr size_t kWsNeedSplit = OUT2_OFF + 4 * (size_t)kNSamples;  // ~2.33 MB
}  // namespace

// Setup: blocks [0,64) rank-sort + coefs; blocks [64,136) table.
// rank[g] = #{h : (onset[h],h) < (onset[g],g)} -- deterministic, no atomics.
// max(amps) == amps[0] (amps strictly decreasing in g).
// Table entry e (= l + kGuard): {phase_l, sin^2(pi*l/L)}; guards {0,0} =>
// OOB contributions vanish (w2=0) with no mask in the hot loop.
__global__ __launch_bounds__(256) void k_setup(const float* __restrict__ dens_p,
                                               const float* __restrict__ slope_p,
                                               const float* __restrict__ f0,
                                               const int* __restrict__ onsets,
                                               void* wsv) {
  char* ws = (char*)wsv;
  const int tid = threadIdx.x;

  if (blockIdx.x >= 64) {
    const int e = (blockIdx.x - 64) * 256 + tid;
    const int l = e - kGuard;
    float2 v = make_float2(0.0f, 0.0f);
    if ((unsigned)l < (unsigned)kGrainN) {
      const double ts    = (double)slope_p[0];
      const double gamma = tan(ts * M_PI / 2.0) * (44100.0 / (12.0 * 256.0)) / 4.0;
      const float  tf    = (float)l / 44100.0f - 0.18575963718820862f;  // ref f32 t
      const double ph = (gamma == 0.0) ? (double)tf
                                       : expm1(gamma * (double)tf) / gamma;
      const double wv = sin(M_PI * ((double)l / 16384.0));
      v = make_float2((float)ph, (float)(wv * wv));
    }
    ((float2*)(ws + TAB_OFF))[e] = v;
    return;
  }

  __shared__ int sons[kNGrains];        // 16 KB
  __shared__ int srank[64][5];          // padded

  for (int i = tid; i < kNGrains; i += 256) sons[i] = onsets[i];
  __syncthreads();

  const int gi = tid & 63;
  const int g  = blockIdx.x * 64 + gi;
  const int ck = tid >> 6;              // 0..3
  const int og = sons[g];

  int pr = 0;
  const int h0 = ck * 1024;
#pragma unroll 8
  for (int h = h0; h < h0 + 1024; ++h) {
    const int oh = sons[h];
    pr += (int)(oh < og) | ((int)(oh == og) & (int)(h < g));
  }
  srank[gi][ck] = pr;
  __syncthreads();

  if (tid < 64) {
    const int gg   = blockIdx.x * 64 + tid;
    const int rank = srank[tid][0] + srank[tid][1] + srank[tid][2] + srank[tid][3];

    const double d    = (double)dens_p[0];
    const double off  = 0.25 * d + 0.75 * d * d;
    const double c2   = 2.0 * (1.0 - d) * 4096.0;
    const double amp  = 1.0 / (1.0 + exp(c2 * ((double)gg / 4096.0 - off)));
    const double amp0 = 1.0 / (1.0 + exp(c2 * (0.0 - off)));  // max amp

    const float f0g = f0[gg];
    const float cg  = (float)(amp / amp0) / sqrtf(f0g);
    ((int*)(ws + ONS_OFF))[rank]   = sons[gg];
    ((float4*)(ws + GR_OFF))[rank] = make_float4(__int_as_float(sons[gg]), f0g, cg, 0.0f);
  }
}

// Main: 2 ADJACENT samples/thread (p0 = s + 2*tid). SPLIT blocks per tile,
// each handling a 1/SPLIT slice of the tile's sorted grain range (8 blocks/CU
// at SPLIT=2 -> max waves/SIMD). Per grain-iter: one ds_read_b128 (params,
// padded -> no min), two global_load_dwordx2 from the SAME SGPR base hitting
// an L1-resident sliding window. Queues: params depth 4, table depth 3.
template <int SPLIT>
__global__ __launch_bounds__(256, 8) void k_main(const int* __restrict__ ONS,
                                                 const float4* __restrict__ GR,
                                                 const float2* __restrict__ TAB2,
                                                 float* __restrict__ out0,
                                                 float* __restrict__ out1) {
  __shared__ float4 sg[kChunk + 8];   // staged grain records + pad

  const int bid  = blockIdx.x;
  const int tile = bid / SPLIT;
  const int half = bid % SPLIT;
  const int tid  = threadIdx.x;
  const int s    = tile * kTile;
  float* __restrict__ dst = (SPLIT == 2 && half == 1) ? out1 : out0;

  // grains overlapping [s, s+kTile): onset in (s - kGrainN, s + kTile - 1]
  int lo, hi;
  {
    int a = 0, b = kNGrains;
    const int t1 = s - kGrainN;
    while (a < b) { int m = (a + b) >> 1; if (ONS[m] > t1) b = m; else a = m + 1; }
    lo = a;
    a = lo; b = kNGrains;
    const int t2 = s + kTile - 1;
    while (a < b) { int m = (a + b) >> 1; if (ONS[m] > t2) b = m; else a = m + 1; }
    hi = a;
  }
  lo = __builtin_amdgcn_readfirstlane(lo);
  hi = __builtin_amdgcn_readfirstlane(hi);

  // this block's slice of the grain range
  const int n_all = hi - lo;
  const int b0g   = lo + (n_all * half) / SPLIT;
  const int e0g   = lo + (n_all * (half + 1)) / SPLIT;

  const int p0 = s + 2 * tid;                 // samples p0, p0+1
  const float2* TG = TAB2 + kGuard;           // entry l at TG[l]
  float acc0 = 0.0f, acc1 = 0.0f;

  for (int base = b0g; base < e0g; base += kChunk) {
    const int n = min(kChunk, e0g - base);    // uniform
    __syncthreads();
    for (int i = tid; i < n; i += 256) sg[i] = GR[base + i];
    if (tid < 8) sg[n + tid] = GR[min(base + n + tid, e0g - 1)];  // valid pad
    __syncthreads();

    // prologue: params 0..3, table values for grains 0..2 (pad makes all valid)
    float4 q0 = sg[0], q1 = sg[1], q2 = sg[2], q3 = sg[3];
    const float2* pT0 = TG - __builtin_amdgcn_readfirstlane(__float_as_int(q0.x));
    const float2* pT1 = TG - __builtin_amdgcn_readfirstlane(__float_as_int(q1.x));
    const float2* pT2 = TG - __builtin_amdgcn_readfirstlane(__float_as_int(q2.x));
    float2 u0a = pT0[p0], u0b = pT0[p0 + 1];
    float2 u1a = pT1[p0], u1b = pT1[p0 + 1];
    float2 u2a = pT2[p0], u2b = pT2[p0 + 1];

#pragma unroll 4
    for (int j = 0; j < n; ++j) {
      // issue: params j+4 (LDS), table pair for grain j+3 (global, L1-hot)
      const float4 qn = sg[j + 4];
      const float2* pT = TG - __builtin_amdgcn_readfirstlane(__float_as_int(q3.x));
      const float2 na = pT[p0];
      const float2 nb = pT[p0 + 1];

      // compute grain j (params 4 iters old, table values 3 iters old)
      const float f0v = q0.y, cv = q0.z;
      acc0 = fmaf(cv * u0a.y,
                  __builtin_amdgcn_sinf(__builtin_amdgcn_fractf(f0v * u0a.x)), acc0);
      acc1 = fmaf(cv * u0b.y,
                  __builtin_amdgcn_sinf(__builtin_amdgcn_fractf(f0v * u0b.x)), acc1);

      // rotate queues (renamed by unroll)
      q0 = q1; q1 = q2; q2 = q3; q3 = qn;
      u0a = u1a; u0b = u1b; u1a = u2a; u1b = u2b; u2a = na; u2b = nb;
    }
  }

  // adjacent-sample float2 store (8B aligned: p0 even)
  *reinterpret_cast<float2*>(dst + p0) = make_float2(acc0, acc1);
}

// Combine halves (if COMBINE) and compute per-block sum of squares (f64).
// 512 blocks x 256 threads x 1 float4 = full signal.
template <bool COMBINE>
__global__ __launch_bounds__(256) void k_norm(float4* __restrict__ outA,
                                              const float4* __restrict__ outB,
                                              double* __restrict__ partials) {
  __shared__ double wpart[4];
  const int tid = threadIdx.x;
  const int i   = blockIdx.x * 256 + tid;
  float4 v = outA[i];
  if (COMBINE) {
    const float4 w = outB[i];
    v.x += w.x; v.y += w.y; v.z += w.z; v.w += w.w;
    outA[i] = v;
  }
  double p2 = (double)v.x * v.x + (double)v.y * v.y +
              (double)v.z * v.z + (double)v.w * v.w;
  for (int off2 = 32; off2 > 0; off2 >>= 1) p2 += __shfl_down(p2, off2);
  if ((tid & 63) == 0) wpart[tid >> 6] = p2;
  __syncthreads();
  if (tid == 0) partials[blockIdx.x] = wpart[0] + wpart[1] + wpart[2] + wpart[3];
}

// Every block reduces the same 512 partials in the same order (deterministic,
// identical result), then scales its 1024-sample chunk by 1/sqrt(sum).
__global__ __launch_bounds__(256) void k_scale(const double* __restrict__ partials,
                                               float4* __restrict__ out) {
  __shared__ double red[256];
  const int tid = threadIdx.x;
  red[tid] = partials[tid] + partials[tid + 256];
  __syncthreads();
  for (int st = 128; st > 0; st >>= 1) {
    if (tid < st) red[tid] += red[tid + st];
    __syncthreads();
  }
  const float sc = (float)(1.0 / sqrt(red[0]));
  const int i = blockIdx.x * 256 + tid;
  float4 v = out[i];
  v.x *= sc; v.y *= sc; v.z *= sc; v.w *= sc;
  out[i] = v;
}

extern "C" void kernel_launch(void* const* d_in, const int* in_sizes, int n_in,
                              void* d_out, int out_size, void* d_ws, size_t ws_size,
                              hipStream_t stream) {
  const float* dens   = (const float*)d_in[0];
  const float* slope  = (const float*)d_in[1];
  const float* f0     = (const float*)d_in[2];
  const int*   onsets = (const int*)d_in[3];
  float* out = (float*)d_out;
  char*  ws  = (char*)d_ws;

  const int*    ONS  = (const int*)(ws + ONS_OFF);
  const float4* GR   = (const float4*)(ws + GR_OFF);
  const float2* TAB2 = (const float2*)(ws + TAB_OFF);
  double*       PART = (double*)(ws + PART_OFF);
  float*        out2 = (float*)(ws + OUT2_OFF);

  hipLaunchKernelGGL(k_setup, dim3(64 + kTabN / 256), dim3(256), 0, stream,
                     dens, slope, f0, onsets, d_ws);

  if (ws_size >= kWsNeedSplit) {
    // split path: 2 blocks per tile -> 8 blocks/CU (max waves/SIMD)
    hipLaunchKernelGGL(k_main<2>, dim3(kNTiles * 2), dim3(256), 0, stream,
                       ONS, GR, TAB2, out, out2);
    hipLaunchKernelGGL(k_norm<true>, dim3(kNSamples / 1024), dim3(256), 0, stream,
                       (float4*)out, (const float4*)out2, PART);
  } else {
    // fallback: proven single-block-per-tile path
    hipLaunchKernelGGL(k_main<1>, dim3(kNTiles), dim3(256), 0, stream,
                       ONS, GR, TAB2, out, out2);
    hipLaunchKernelGGL(k_norm<false>, dim3(kNSamples / 1024), dim3(256), 0, stream,
                       (float4*)out, (const float4*)nullptr, PART);
  }
  hipLaunchKernelGGL(k_scale, dim3(kNSamples / 1024), dim3(256), 0, stream,
                     PART, (float4*)out);
}